// Round 7
// baseline (395.311 us; speedup 1.0000x reference)
//
#include <hip/hip_runtime.h>
#include <cstdint>
#include <cstddef>

// DCNv2 x2 (B=2, C=O=256, H=W=96, k=3), fully fused per layer.
// R18: R17 showed 2 blocks/CU never materialized (81920B x2 = exactly 160KB
// -> HW won't pack; occupancy stayed 25%). Fix: A-panel LDS is WAVE-PRIVATE
// (each wave DMAs + reads only its own 4KB slice), so the A double-buffer is
// unnecessary: single Abuf (32KB) with per-wave overwrite-after-own-read
// (explicit lgkmcnt(0)+sched_barrier before DMA; round barrier drains vmcnt
// before next read). LDS 81664 -> 48896B -> THREE blocks/CU, grid 576 fully
// resident in ONE pass (no serial tail; cross-block overlap hides drains).
// launch_bounds(512,6) caps VGPR at 85 for 24 waves/CU.
// offconv/transpose/preps unchanged. k' = kk*256 + c. XCD swizzle: g%8.

#define KTOT 2304
#define PXB  9216

typedef __attribute__((ext_vector_type(8))) short bf16x8;
typedef __attribute__((ext_vector_type(4))) float f32x4;

static __device__ __forceinline__ unsigned short f2bf(float f) {
    union { float f; unsigned int u; } v; v.f = f;
    unsigned int r = (v.u + 0x7FFFu + ((v.u >> 16) & 1u)) >> 16;
    return (unsigned short)r;
}
static __device__ __forceinline__ float bf2f(unsigned short h) {
    union { unsigned int u; float f; } v; v.u = ((unsigned int)h) << 16;
    return v.f;
}
// unpack 8 bf16 (uint4) -> 8 fp32; 1 bit-op per element
static __device__ __forceinline__ void unpack8(uint4 u, float* f) {
    union { unsigned int u; float f; } t;
    t.u = u.x << 16;         f[0] = t.f;
    t.u = u.x & 0xffff0000u; f[1] = t.f;
    t.u = u.y << 16;         f[2] = t.f;
    t.u = u.y & 0xffff0000u; f[3] = t.f;
    t.u = u.z << 16;         f[4] = t.f;
    t.u = u.z & 0xffff0000u; f[5] = t.f;
    t.u = u.w << 16;         f[6] = t.f;
    t.u = u.w & 0xffff0000u; f[7] = t.f;
}

// ---------------------------------------------------------------------------
// NCHW -> NHWC transpose, hi/lo bf16 outputs
// ---------------------------------------------------------------------------
__global__ __launch_bounds__(256) void transpose_kernel(const float* __restrict__ in,
                                                        unsigned short* __restrict__ outH,
                                                        unsigned short* __restrict__ outL) {
    __shared__ float tile[64][65];
    const int hw0 = blockIdx.x * 64;
    const int c0  = blockIdx.y * 64;
    const int b   = blockIdx.z;
    const int lx  = threadIdx.x & 63;
    const int ly  = threadIdx.x >> 6;
#pragma unroll
    for (int i = 0; i < 16; ++i) {
        int cl = ly + i * 4;
        tile[cl][lx] = in[(size_t)(b * 256 + c0 + cl) * PXB + hw0 + lx];
    }
    __syncthreads();
#pragma unroll
    for (int i = 0; i < 16; ++i) {
        int hwl = ly + i * 4;
        float v = tile[lx][hwl];
        size_t oi = ((size_t)b * PXB + hw0 + hwl) * 256 + c0 + lx;
        unsigned short hi = f2bf(v);
        outH[oi] = hi;
        outL[oi] = f2bf(v - bf2f(hi));
    }
}

// ---------------------------------------------------------------------------
// Main weight prep: w[o][c][kk] fp32 -> wA[o][k'=kk*256+c] bf16
// ---------------------------------------------------------------------------
__global__ __launch_bounds__(256) void prep_w_kernel(const float* __restrict__ w,
                                                     unsigned short* __restrict__ wA) {
    int idx = blockIdx.x * 256 + threadIdx.x;   // 256*2304
    int o = idx / KTOT;
    int k = idx - o * KTOT;
    int kk = k >> 8;
    int c  = k & 255;
    wA[idx] = f2bf(w[o * KTOT + c * 9 + kk]);
}

// ---------------------------------------------------------------------------
// Offset weight prep (split): rows 27..32 zero. hi = bf16(w), lo = bf16(w-hi).
// ---------------------------------------------------------------------------
__global__ __launch_bounds__(256) void prep_woff_kernel(const float* __restrict__ w,
                                                        unsigned short* __restrict__ wH,
                                                        unsigned short* __restrict__ wL) {
    int idx = blockIdx.x * 256 + threadIdx.x;   // 32*2304
    int o = idx / KTOT;
    int k = idx - o * KTOT;
    int kk = k >> 8;
    int c  = k & 255;
    float f = (o < 27) ? w[o * KTOT + c * 9 + kk] : 0.0f;
    unsigned short hi = f2bf(f);
    wH[idx] = hi;
    wL[idx] = f2bf(f - bf2f(hi));
}

// ---------------------------------------------------------------------------
// Fused offset conv: M=32(27) x N=64px x K=2304, split-bf16 3-term. (R12)
// ---------------------------------------------------------------------------
__global__ __launch_bounds__(512) void offconv_fused(const unsigned short* __restrict__ xH,
                                                     const unsigned short* __restrict__ xL,
                                                     const unsigned short* __restrict__ AH,
                                                     const unsigned short* __restrict__ AL,
                                                     const float* __restrict__ bias,
                                                     float* __restrict__ om) {
    __shared__ __attribute__((aligned(16))) unsigned short AsH[2][32 * 72];
    __shared__ __attribute__((aligned(16))) unsigned short AsL[2][32 * 72];
    __shared__ __attribute__((aligned(16))) unsigned short BsH[2][64 * 72];
    __shared__ __attribute__((aligned(16))) unsigned short BsL[2][64 * 72];

    const int tid  = threadIdx.x;
    const int kg   = tid >> 8;
    const int tl   = tid & 255;
    const int lane = tid & 63;
    const int wq   = (tid >> 6) & 3;
    const int quad = lane >> 4, l16 = lane & 15;
    const int g    = blockIdx.x;            // 288
    const int nb   = (g & 7) * 36 + (g >> 3);
    const int n0   = nb * 64;
    const int b    = n0 / PXB;
    const int hw0  = n0 - b * PXB;

    f32x4 acc[2];
#pragma unroll
    for (int mt = 0; mt < 2; ++mt) acc[mt] = (f32x4)0.0f;

    const int arow = tl >> 3, akg = tl & 7;

    uint4 pAH, pAL, pBH0, pBL0, pBH1, pBL1;
    auto pf = [&](int it) {
        const int kt = kg * 18 + it;
        const int kk = kt >> 2, c0 = (kt & 3) * 64;
        const int dy = kk / 3 - 1, dx = kk - (kk / 3) * 3 - 1;
        size_t ai = (size_t)arow * KTOT + kt * 64 + akg * 8;
        pAH = *(const uint4*)&AH[ai];
        pAL = *(const uint4*)&AL[ai];
#pragma unroll
        for (int i = 0; i < 2; ++i) {
            int task = i * 256 + tl;
            int px = task >> 3, cg = task & 7;
            int hw = hw0 + px;
            int h = hw / 96, w = hw - h * 96;
            int y = h + dy, x = w + dx;
            uint4 hv = make_uint4(0u, 0u, 0u, 0u), lv = make_uint4(0u, 0u, 0u, 0u);
            if (((unsigned)y < 96u) && ((unsigned)x < 96u)) {
                size_t bi = ((size_t)b * PXB + y * 96 + x) * 256 + c0 + cg * 8;
                hv = *(const uint4*)&xH[bi];
                lv = *(const uint4*)&xL[bi];
            }
            if (i == 0) { pBH0 = hv; pBL0 = lv; } else { pBH1 = hv; pBL1 = lv; }
        }
    };
    pf(0);

    for (int it = 0; it < 18; ++it) {
        __syncthreads();
        *(uint4*)&AsH[kg][arow * 72 + akg * 8] = pAH;
        *(uint4*)&AsL[kg][arow * 72 + akg * 8] = pAL;
        {
            int px = tl >> 3, cg = tl & 7;
            *(uint4*)&BsH[kg][px * 72 + cg * 8] = pBH0;
            *(uint4*)&BsL[kg][px * 72 + cg * 8] = pBL0;
        }
        {
            int task = 256 + tl;
            int px = task >> 3, cg = task & 7;
            *(uint4*)&BsH[kg][px * 72 + cg * 8] = pBH1;
            *(uint4*)&BsL[kg][px * 72 + cg * 8] = pBL1;
        }
        if (it < 17) pf(it + 1);
        __syncthreads();
#pragma unroll
        for (int ks = 0; ks < 2; ++ks) {
            bf16x8 ah[2], al[2], bh, bl;
#pragma unroll
            for (int mt = 0; mt < 2; ++mt) {
                ah[mt] = *(const bf16x8*)&AsH[kg][(mt * 16 + l16) * 72 + ks * 32 + quad * 8];
                al[mt] = *(const bf16x8*)&AsL[kg][(mt * 16 + l16) * 72 + ks * 32 + quad * 8];
            }
            bh = *(const bf16x8*)&BsH[kg][(wq * 16 + l16) * 72 + ks * 32 + quad * 8];
            bl = *(const bf16x8*)&BsL[kg][(wq * 16 + l16) * 72 + ks * 32 + quad * 8];
#pragma unroll
            for (int mt = 0; mt < 2; ++mt) {
                acc[mt] = __builtin_amdgcn_mfma_f32_16x16x32_bf16(ah[mt], bh, acc[mt], 0, 0, 0);
                acc[mt] = __builtin_amdgcn_mfma_f32_16x16x32_bf16(ah[mt], bl, acc[mt], 0, 0, 0);
                acc[mt] = __builtin_amdgcn_mfma_f32_16x16x32_bf16(al[mt], bh, acc[mt], 0, 0, 0);
            }
        }
    }

    float* red = (float*)BsH;
    __syncthreads();
    if (kg == 1) {
#pragma unroll
        for (int mt = 0; mt < 2; ++mt)
#pragma unroll
            for (int r = 0; r < 4; ++r)
                red[wq * 512 + mt * 256 + quad * 64 + r * 16 + l16] = acc[mt][r];
    }
    __syncthreads();
    if (kg == 0) {
#pragma unroll
        for (int mt = 0; mt < 2; ++mt)
#pragma unroll
            for (int r = 0; r < 4; ++r) {
                float v = acc[mt][r] + red[wq * 512 + mt * 256 + quad * 64 + r * 16 + l16];
                int m = mt * 16 + quad * 4 + r;
                int n = wq * 16 + l16;
                if (m < 27)
                    om[(size_t)(b * 27 + m) * PXB + hw0 + n] = v + bias[m];
            }
    }
}

// ---------------------------------------------------------------------------
// Fused deformable conv v2 (both layers): M=256 x N=32, 36 rounds x K=64.
// A: SINGLE-buffered wave-private LDS (32KB), global_load_lds DMA; a wave
// overwrites its own region only after its own A ds_reads completed
// (lgkmcnt(0)+sched_barrier before DMA; round barrier drains vmcnt).
// B: dbuf panel. ONE __syncthreads per round. LDS 48896B -> 3 blocks/CU.
// out_mode 0: NCHW fp32. out_mode 1: NHWC hi/lo bf16 (outH/outL).
// ---------------------------------------------------------------------------
__global__ __launch_bounds__(512, 6) void dfconv_v2(const unsigned short* __restrict__ xB,
                                                    const float* __restrict__ om,
                                                    const unsigned short* __restrict__ A,
                                                    float* __restrict__ out,
                                                    unsigned short* __restrict__ outH,
                                                    unsigned short* __restrict__ outL,
                                                    int out_mode) {
    // arena: Abuf [8][4096]B @0 (32768) | Bbuf0 @32768 (4608) |
    //        Bbuf1 @37376 (4608) | goff @41984 (2304) | gwt @44288 (4608)
    __shared__ __attribute__((aligned(16))) char smem[48896];
    unsigned short* Bbuf0 = (unsigned short*)(smem + 32768);
    unsigned short* Bbuf1 = (unsigned short*)(smem + 37376);
    unsigned short* goff  = (unsigned short*)(smem + 41984);
    float*          gwt   = (float*)(smem + 44288);

    const int tid  = threadIdx.x;
    const int wv   = tid >> 6;
    const int lane = tid & 63;
    const int quad = lane >> 4, l16 = lane & 15;
    const int g    = blockIdx.x;            // 576
    const int nb   = (g & 7) * 72 + (g >> 3);
    const int n0   = nb * 32;
    const int b    = n0 / PXB;
    const int hw0  = n0 - b * PXB;

    // ---- geometry: 32 px x 9 taps ----
    if (tid < 288) {
        int task = tid;
        int px = task / 9;
        int kk = task - px * 9;
        int hw = hw0 + px;
        int h = hw / 96, w = hw - h * 96;
        const float* omp = om + (size_t)b * 27 * PXB + hw;
        float dyv = omp[(size_t)(2 * kk) * PXB];
        float dxv = omp[(size_t)(2 * kk + 1) * PXB];
        float mv  = omp[(size_t)(18 + kk) * PXB];
        float mk  = 1.0f / (1.0f + __expf(-mv));

        float ys = (float)(h + (kk / 3) - 1) + dyv;
        float xs = (float)(w + (kk - (kk / 3) * 3) - 1) + dxv;
        float fy = floorf(ys), fx = floorf(xs);
        int iy = (int)fy, ix = (int)fx;
        float wy1 = ys - fy, wx1 = xs - fx;
        float wy0 = 1.0f - wy1, wx0 = 1.0f - wx1;
        bool yv0 = (unsigned)iy < 96u, yv1 = (unsigned)(iy + 1) < 96u;
        bool xv0 = (unsigned)ix < 96u, xv1 = (unsigned)(ix + 1) < 96u;
        int y0 = min(max(iy, 0), 95),     y1 = min(max(iy + 1, 0), 95);
        int x0 = min(max(ix, 0), 95),     x1 = min(max(ix + 1, 0), 95);
        int gg = task * 4;
        goff[gg + 0] = (unsigned short)(y0 * 96 + x0);
        goff[gg + 1] = (unsigned short)(y0 * 96 + x1);
        goff[gg + 2] = (unsigned short)(y1 * 96 + x0);
        goff[gg + 3] = (unsigned short)(y1 * 96 + x1);
        gwt[gg + 0] = (yv0 && xv0) ? mk * wy0 * wx0 : 0.0f;
        gwt[gg + 1] = (yv0 && xv1) ? mk * wy0 * wx1 : 0.0f;
        gwt[gg + 2] = (yv1 && xv0) ? mk * wy1 * wx0 : 0.0f;
        gwt[gg + 3] = (yv1 && xv1) ? mk * wy1 * wx1 : 0.0f;
    }
    __syncthreads();

    // ---- roles ----
    const int px = (tid & 255) >> 3;        // staging (tid<256)
    const int cg = tid & 7;
    const unsigned short* xbase = xB + (size_t)b * PXB * 256 + cg * 8;

    // A DMA lane mapping: shot s covers rows wv*32+s*8+(lane>>3); granule slot
    // lane&7 holds global granule (lane&7)^(lane>>3)  [XOR source swizzle].
    const int arl = lane >> 3;               // 0..7
    const int akg = (lane & 7) ^ arl;        // swizzled source granule

    f32x4 acc[2][2];
#pragma unroll
    for (int mt = 0; mt < 2; ++mt)
#pragma unroll
        for (int nt = 0; nt < 2; ++nt) acc[mt][nt] = (f32x4)0.0f;

    auto dmaA = [&](int kt) {
#pragma unroll
        for (int s = 0; s < 4; ++s) {
            const unsigned short* src =
                A + (size_t)(wv * 32 + s * 8 + arl) * KTOT + kt * 64 + akg * 8;
            char* dst = smem + wv * 4096 + s * 1024;
            __builtin_amdgcn_global_load_lds(
                (const __attribute__((address_space(1))) unsigned int*)src,
                (__attribute__((address_space(3))) unsigned int*)dst, 16, 0, 0);
        }
    };

    // ---- prologue: A(0) DMA, corners(0) -> interp -> Bbuf0 ----
    dmaA(0);
    if (tid < 256) {
        int gg = (px * 9 + 0) * 4;          // kt=0: tap 0, c0 0
        ushort4 o4 = *(const ushort4*)&goff[gg];
        float4 wt = *(const float4*)&gwt[gg];
        uint4 u0 = *(const uint4*)(xbase + (size_t)o4.x * 256);
        uint4 u1 = *(const uint4*)(xbase + (size_t)o4.y * 256);
        uint4 u2 = *(const uint4*)(xbase + (size_t)o4.z * 256);
        uint4 u3 = *(const uint4*)(xbase + (size_t)o4.w * 256);
        float f0[8], f1[8], f2[8], f3[8];
        unpack8(u0, f0); unpack8(u1, f1); unpack8(u2, f2); unpack8(u3, f3);
        unsigned short res[8];
#pragma unroll
        for (int j = 0; j < 8; ++j)
            res[j] = f2bf(wt.x * f0[j] + wt.y * f1[j] + wt.z * f2[j] + wt.w * f3[j]);
        *(uint4*)&Bbuf0[px * 72 + cg * 8] = *(uint4*)res;
    }
    __syncthreads();    // A(0) drained, B(0) visible

    // ---- main loop: ONE barrier per round, single wave-private Abuf ----
    for (int r = 0; r < 36; ++r) {
        const int cur = r & 1;

        // 1. issue next round's corners (max latency cover)
        uint4 cc0, cc1, cc2, cc3; float4 wt;
        if (tid < 256 && r < 35) {
            const int ktn = r + 1, tap = ktn >> 2, c0 = (ktn & 3) * 64;
            int gg = (px * 9 + tap) * 4;
            ushort4 o4 = *(const ushort4*)&goff[gg];
            wt = *(const float4*)&gwt[gg];
            const unsigned short* cb = xbase + c0;
            cc0 = *(const uint4*)(cb + (size_t)o4.x * 256);
            cc1 = *(const uint4*)(cb + (size_t)o4.y * 256);
            cc2 = *(const uint4*)(cb + (size_t)o4.z * 256);
            cc3 = *(const uint4*)(cb + (size_t)o4.w * 256);
        }

        // 2. A-fragments: LDS -> regs (wave-private region)
        bf16x8 af00, af01, af10, af11;
        {
            const char* Ac = smem + wv * 4096;
            const int sw0 = ((quad ^ (l16 & 7)) * 16);
            const int sw1 = (((4 + quad) ^ (l16 & 7)) * 16);
            af00 = *(const bf16x8*)(Ac + l16 * 128 + sw0);
            af01 = *(const bf16x8*)(Ac + (16 + l16) * 128 + sw0);
            af10 = *(const bf16x8*)(Ac + l16 * 128 + sw1);
            af11 = *(const bf16x8*)(Ac + (16 + l16) * 128 + sw1);
        }
        // A reads complete before overwrite; fence per rule #18
        asm volatile("s_waitcnt lgkmcnt(0)" ::: "memory");
        __builtin_amdgcn_sched_barrier(0);

        // 3. DMA A(r+1) into the SAME wave-private region (safe post-read)
        if (r < 35) dmaA(r + 1);

        // 4. MFMA (A from regs, B from LDS)
        {
            const unsigned short* Br = cur ? Bbuf1 : Bbuf0;
            bf16x8 b0 = *(const bf16x8*)&Br[l16 * 72 + quad * 8];
            bf16x8 b1 = *(const bf16x8*)&Br[(16 + l16) * 72 + quad * 8];
            acc[0][0] = __builtin_amdgcn_mfma_f32_16x16x32_bf16(af00, b0, acc[0][0], 0, 0, 0);
            acc[0][1] = __builtin_amdgcn_mfma_f32_16x16x32_bf16(af00, b1, acc[0][1], 0, 0, 0);
            acc[1][0] = __builtin_amdgcn_mfma_f32_16x16x32_bf16(af01, b0, acc[1][0], 0, 0, 0);
            acc[1][1] = __builtin_amdgcn_mfma_f32_16x16x32_bf16(af01, b1, acc[1][1], 0, 0, 0);
            bf16x8 b2 = *(const bf16x8*)&Br[l16 * 72 + 32 + quad * 8];
            bf16x8 b3 = *(const bf16x8*)&Br[(16 + l16) * 72 + 32 + quad * 8];
            acc[0][0] = __builtin_amdgcn_mfma_f32_16x16x32_bf16(af10, b2, acc[0][0], 0, 0, 0);
            acc[0][1] = __builtin_amdgcn_mfma_f32_16x16x32_bf16(af10, b3, acc[0][1], 0, 0, 0);
            acc[1][0] = __builtin_amdgcn_mfma_f32_16x16x32_bf16(af11, b2, acc[1][0], 0, 0, 0);
            acc[1][1] = __builtin_amdgcn_mfma_f32_16x16x32_bf16(af11, b3, acc[1][1], 0, 0, 0);
        }

        // 5. interp next round's corners -> other B buffer
        if (tid < 256 && r < 35) {
            unsigned short* Bw = cur ? Bbuf0 : Bbuf1;
            float f0[8], f1[8], f2[8], f3[8];
            unpack8(cc0, f0); unpack8(cc1, f1); unpack8(cc2, f2); unpack8(cc3, f3);
            unsigned short res[8];
#pragma unroll
            for (int j = 0; j < 8; ++j)
                res[j] = f2bf(wt.x * f0[j] + wt.y * f1[j] + wt.z * f2[j] + wt.w * f3[j]);
            *(uint4*)&Bw[px * 72 + cg * 8] = *(uint4*)res;
        }

        __syncthreads();    // DMA drained (A(r+1) ready), B(next) visible
    }

    // ---- epilogues: tileS aliases smem ----
    float* tileS = (float*)smem;
    if (out_mode == 0) {
        // NCHW out[b][m][hw0..+31]: 2 passes of 128 m; tileS[128][36]
#pragma unroll
        for (int pass = 0; pass < 2; ++pass) {
            if ((wv >> 2) == pass) {
#pragma unroll
                for (int mt = 0; mt < 2; ++mt)
#pragma unroll
                    for (int nt = 0; nt < 2; ++nt)
#pragma unroll
                        for (int rr = 0; rr < 4; ++rr) {
                            int ml = (wv & 3) * 32 + mt * 16 + quad * 4 + rr;
                            int n  = nt * 16 + l16;
                            tileS[ml * 36 + n] = fmaxf(acc[mt][nt][rr], 0.0f);
                        }
            }
            __syncthreads();
#pragma unroll
            for (int j = 0; j < 2; ++j) {
                int idx = j * 512 + tid;
                int row = idx >> 3, q = idx & 7;
                *(float4*)&out[(size_t)(b * 256 + pass * 128 + row) * PXB + hw0 + q * 4] =
                    *(const float4*)&tileS[row * 36 + q * 4];
            }
            __syncthreads();
        }
    } else {
        // NHWC hi/lo bf16 (outH/outL): 2 passes of 16 px; tileS[16][264]
#pragma unroll
        for (int pass = 0; pass < 2; ++pass) {
#pragma unroll
            for (int mt = 0; mt < 2; ++mt) {
                f32x4 v = acc[mt][pass];
                v[0] = fmaxf(v[0], 0.f); v[1] = fmaxf(v[1], 0.f);
                v[2] = fmaxf(v[2], 0.f); v[3] = fmaxf(v[3], 0.f);
                *(f32x4*)&tileS[l16 * 264 + wv * 32 + mt * 16 + quad * 4] = v;
            }
            __syncthreads();
#pragma unroll
            for (int j = 0; j < 2; ++j) {
                int idx = j * 512 + tid;
                int pxl = idx >> 6, ln = idx & 63;
                float4 v = *(const float4*)&tileS[pxl * 264 + ln * 4];
                size_t oi = ((size_t)b * PXB + hw0 + pass * 16 + pxl) * 256 + ln * 4;
                unsigned short hv[4], lv[4];
#pragma unroll
                for (int e = 0; e < 4; ++e) {
                    float fe = (e == 0) ? v.x : (e == 1) ? v.y : (e == 2) ? v.z : v.w;
                    hv[e] = f2bf(fe);
                    lv[e] = f2bf(fe - bf2f(hv[e]));
                }
                *(ushort4*)&outH[oi] = *(ushort4*)hv;
                *(ushort4*)&outL[oi] = *(ushort4*)lv;
            }
            __syncthreads();
        }
    }
}

// ---------------------------------------------------------------------------
extern "C" void kernel_launch(void* const* d_in, const int* in_sizes, int n_in,
                              void* d_out, int out_size, void* d_ws, size_t ws_size,
                              hipStream_t stream) {
    const float* x     = (const float*)d_in[0];
    const float* woff0 = (const float*)d_in[1];
    const float* boff0 = (const float*)d_in[2];
    const float* w0    = (const float*)d_in[3];
    const float* woff1 = (const float*)d_in[4];
    const float* boff1 = (const float*)d_in[5];
    const float* w1    = (const float*)d_in[6];
    float* out = (float*)d_out;

    char* p = (char*)d_ws;
    float* om  = (float*)p;  p += (size_t)2 * 27 * PXB * 4;               // 2.0 MB
    unsigned short* xh  = (unsigned short*)p; p += (size_t)2 * 256 * PXB * 2;  // 9.4 MB
    unsigned short* xl  = (unsigned short*)p; p += (size_t)2 * 256 * PXB * 2;  // 9.4 MB
    unsigned short* h1h = (unsigned short*)p; p += (size_t)2 * 256 * PXB * 2;  // 9.4 MB
    unsigned short* h1l = (unsigned short*)p; p += (size_t)2 * 256 * PXB * 2;  // 9.4 MB
    unsigned short* wA0 = (unsigned short*)p; p += (size_t)256 * KTOT * 2;
    unsigned short* wA1 = (unsigned short*)p; p += (size_t)256 * KTOT * 2;
    unsigned short* wH0 = (unsigned short*)p; p += (size_t)32 * KTOT * 2;
    unsigned short* wL0 = (unsigned short*)p; p += (size_t)32 * KTOT * 2;
    unsigned short* wH1 = (unsigned short*)p; p += (size_t)32 * KTOT * 2;
    unsigned short* wL1 = (unsigned short*)p; p += (size_t)32 * KTOT * 2;

    hipLaunchKernelGGL(transpose_kernel, dim3(PXB / 64, 4, 2), dim3(256), 0, stream, x, xh, xl);
    hipLaunchKernelGGL(prep_w_kernel, dim3(256 * KTOT / 256), dim3(256), 0, stream, w0, wA0);
    hipLaunchKernelGGL(prep_w_kernel, dim3(256 * KTOT / 256), dim3(256), 0, stream, w1, wA1);
    hipLaunchKernelGGL(prep_woff_kernel, dim3(32 * KTOT / 256), dim3(256), 0, stream, woff0, wH0, wL0);
    hipLaunchKernelGGL(prep_woff_kernel, dim3(32 * KTOT / 256), dim3(256), 0, stream, woff1, wH1, wL1);

    // Layer 0: x -> h1 (NHWC hi/lo bf16)
    hipLaunchKernelGGL(offconv_fused, dim3(288), dim3(512), 0, stream, xh, xl, wH0, wL0, boff0, om);
    hipLaunchKernelGGL(dfconv_v2, dim3(576), dim3(512), 0, stream, xh, om, wA0,
                       (float*)nullptr, h1h, h1l, 1);

    // Layer 1: h1 -> out (NCHW fp32)
    hipLaunchKernelGGL(offconv_fused, dim3(288), dim3(512), 0, stream, h1h, h1l, wH1, wL1, boff1, om);
    hipLaunchKernelGGL(dfconv_v2, dim3(576), dim3(512), 0, stream, h1h, om, wA1,
                       out, (unsigned short*)nullptr, (unsigned short*)nullptr, 0);
}

// Round 8
// 306.489 us; speedup vs baseline: 1.2898x; 1.2898x over previous
//
#include <hip/hip_runtime.h>
#include <cstdint>
#include <cstddef>

// DCNv2 x2 (B=2, C=O=256, H=W=96, k=3), fully fused per layer.
// R19: R18's (512,6) VGPR cap (~85) spilled the prefetch state to scratch
// (WRITE_SIZE 18->80MB = smoking gun) and regressed 87->132us. Keep the LDS
// shrink (single wave-private Abuf, 48896B -> 2 blocks/CU at 97.8KB) but
// restore (512,4): VGPR cap 128 >> the ~52 actually needed, zero spill.
// Everything else identical to R18.
// offconv/transpose/preps unchanged. k' = kk*256 + c. XCD swizzle: g%8.

#define KTOT 2304
#define PXB  9216

typedef __attribute__((ext_vector_type(8))) short bf16x8;
typedef __attribute__((ext_vector_type(4))) float f32x4;

static __device__ __forceinline__ unsigned short f2bf(float f) {
    union { float f; unsigned int u; } v; v.f = f;
    unsigned int r = (v.u + 0x7FFFu + ((v.u >> 16) & 1u)) >> 16;
    return (unsigned short)r;
}
static __device__ __forceinline__ float bf2f(unsigned short h) {
    union { unsigned int u; float f; } v; v.u = ((unsigned int)h) << 16;
    return v.f;
}
// unpack 8 bf16 (uint4) -> 8 fp32; 1 bit-op per element
static __device__ __forceinline__ void unpack8(uint4 u, float* f) {
    union { unsigned int u; float f; } t;
    t.u = u.x << 16;         f[0] = t.f;
    t.u = u.x & 0xffff0000u; f[1] = t.f;
    t.u = u.y << 16;         f[2] = t.f;
    t.u = u.y & 0xffff0000u; f[3] = t.f;
    t.u = u.z << 16;         f[4] = t.f;
    t.u = u.z & 0xffff0000u; f[5] = t.f;
    t.u = u.w << 16;         f[6] = t.f;
    t.u = u.w & 0xffff0000u; f[7] = t.f;
}

// ---------------------------------------------------------------------------
// NCHW -> NHWC transpose, hi/lo bf16 outputs
// ---------------------------------------------------------------------------
__global__ __launch_bounds__(256) void transpose_kernel(const float* __restrict__ in,
                                                        unsigned short* __restrict__ outH,
                                                        unsigned short* __restrict__ outL) {
    __shared__ float tile[64][65];
    const int hw0 = blockIdx.x * 64;
    const int c0  = blockIdx.y * 64;
    const int b   = blockIdx.z;
    const int lx  = threadIdx.x & 63;
    const int ly  = threadIdx.x >> 6;
#pragma unroll
    for (int i = 0; i < 16; ++i) {
        int cl = ly + i * 4;
        tile[cl][lx] = in[(size_t)(b * 256 + c0 + cl) * PXB + hw0 + lx];
    }
    __syncthreads();
#pragma unroll
    for (int i = 0; i < 16; ++i) {
        int hwl = ly + i * 4;
        float v = tile[lx][hwl];
        size_t oi = ((size_t)b * PXB + hw0 + hwl) * 256 + c0 + lx;
        unsigned short hi = f2bf(v);
        outH[oi] = hi;
        outL[oi] = f2bf(v - bf2f(hi));
    }
}

// ---------------------------------------------------------------------------
// Main weight prep: w[o][c][kk] fp32 -> wA[o][k'=kk*256+c] bf16
// ---------------------------------------------------------------------------
__global__ __launch_bounds__(256) void prep_w_kernel(const float* __restrict__ w,
                                                     unsigned short* __restrict__ wA) {
    int idx = blockIdx.x * 256 + threadIdx.x;   // 256*2304
    int o = idx / KTOT;
    int k = idx - o * KTOT;
    int kk = k >> 8;
    int c  = k & 255;
    wA[idx] = f2bf(w[o * KTOT + c * 9 + kk]);
}

// ---------------------------------------------------------------------------
// Offset weight prep (split): rows 27..32 zero. hi = bf16(w), lo = bf16(w-hi).
// ---------------------------------------------------------------------------
__global__ __launch_bounds__(256) void prep_woff_kernel(const float* __restrict__ w,
                                                        unsigned short* __restrict__ wH,
                                                        unsigned short* __restrict__ wL) {
    int idx = blockIdx.x * 256 + threadIdx.x;   // 32*2304
    int o = idx / KTOT;
    int k = idx - o * KTOT;
    int kk = k >> 8;
    int c  = k & 255;
    float f = (o < 27) ? w[o * KTOT + c * 9 + kk] : 0.0f;
    unsigned short hi = f2bf(f);
    wH[idx] = hi;
    wL[idx] = f2bf(f - bf2f(hi));
}

// ---------------------------------------------------------------------------
// Fused offset conv: M=32(27) x N=64px x K=2304, split-bf16 3-term. (R12)
// ---------------------------------------------------------------------------
__global__ __launch_bounds__(512) void offconv_fused(const unsigned short* __restrict__ xH,
                                                     const unsigned short* __restrict__ xL,
                                                     const unsigned short* __restrict__ AH,
                                                     const unsigned short* __restrict__ AL,
                                                     const float* __restrict__ bias,
                                                     float* __restrict__ om) {
    __shared__ __attribute__((aligned(16))) unsigned short AsH[2][32 * 72];
    __shared__ __attribute__((aligned(16))) unsigned short AsL[2][32 * 72];
    __shared__ __attribute__((aligned(16))) unsigned short BsH[2][64 * 72];
    __shared__ __attribute__((aligned(16))) unsigned short BsL[2][64 * 72];

    const int tid  = threadIdx.x;
    const int kg   = tid >> 8;
    const int tl   = tid & 255;
    const int lane = tid & 63;
    const int wq   = (tid >> 6) & 3;
    const int quad = lane >> 4, l16 = lane & 15;
    const int g    = blockIdx.x;            // 288
    const int nb   = (g & 7) * 36 + (g >> 3);
    const int n0   = nb * 64;
    const int b    = n0 / PXB;
    const int hw0  = n0 - b * PXB;

    f32x4 acc[2];
#pragma unroll
    for (int mt = 0; mt < 2; ++mt) acc[mt] = (f32x4)0.0f;

    const int arow = tl >> 3, akg = tl & 7;

    uint4 pAH, pAL, pBH0, pBL0, pBH1, pBL1;
    auto pf = [&](int it) {
        const int kt = kg * 18 + it;
        const int kk = kt >> 2, c0 = (kt & 3) * 64;
        const int dy = kk / 3 - 1, dx = kk - (kk / 3) * 3 - 1;
        size_t ai = (size_t)arow * KTOT + kt * 64 + akg * 8;
        pAH = *(const uint4*)&AH[ai];
        pAL = *(const uint4*)&AL[ai];
#pragma unroll
        for (int i = 0; i < 2; ++i) {
            int task = i * 256 + tl;
            int px = task >> 3, cg = task & 7;
            int hw = hw0 + px;
            int h = hw / 96, w = hw - h * 96;
            int y = h + dy, x = w + dx;
            uint4 hv = make_uint4(0u, 0u, 0u, 0u), lv = make_uint4(0u, 0u, 0u, 0u);
            if (((unsigned)y < 96u) && ((unsigned)x < 96u)) {
                size_t bi = ((size_t)b * PXB + y * 96 + x) * 256 + c0 + cg * 8;
                hv = *(const uint4*)&xH[bi];
                lv = *(const uint4*)&xL[bi];
            }
            if (i == 0) { pBH0 = hv; pBL0 = lv; } else { pBH1 = hv; pBL1 = lv; }
        }
    };
    pf(0);

    for (int it = 0; it < 18; ++it) {
        __syncthreads();
        *(uint4*)&AsH[kg][arow * 72 + akg * 8] = pAH;
        *(uint4*)&AsL[kg][arow * 72 + akg * 8] = pAL;
        {
            int px = tl >> 3, cg = tl & 7;
            *(uint4*)&BsH[kg][px * 72 + cg * 8] = pBH0;
            *(uint4*)&BsL[kg][px * 72 + cg * 8] = pBL0;
        }
        {
            int task = 256 + tl;
            int px = task >> 3, cg = task & 7;
            *(uint4*)&BsH[kg][px * 72 + cg * 8] = pBH1;
            *(uint4*)&BsL[kg][px * 72 + cg * 8] = pBL1;
        }
        if (it < 17) pf(it + 1);
        __syncthreads();
#pragma unroll
        for (int ks = 0; ks < 2; ++ks) {
            bf16x8 ah[2], al[2], bh, bl;
#pragma unroll
            for (int mt = 0; mt < 2; ++mt) {
                ah[mt] = *(const bf16x8*)&AsH[kg][(mt * 16 + l16) * 72 + ks * 32 + quad * 8];
                al[mt] = *(const bf16x8*)&AsL[kg][(mt * 16 + l16) * 72 + ks * 32 + quad * 8];
            }
            bh = *(const bf16x8*)&BsH[kg][(wq * 16 + l16) * 72 + ks * 32 + quad * 8];
            bl = *(const bf16x8*)&BsL[kg][(wq * 16 + l16) * 72 + ks * 32 + quad * 8];
#pragma unroll
            for (int mt = 0; mt < 2; ++mt) {
                acc[mt] = __builtin_amdgcn_mfma_f32_16x16x32_bf16(ah[mt], bh, acc[mt], 0, 0, 0);
                acc[mt] = __builtin_amdgcn_mfma_f32_16x16x32_bf16(ah[mt], bl, acc[mt], 0, 0, 0);
                acc[mt] = __builtin_amdgcn_mfma_f32_16x16x32_bf16(al[mt], bh, acc[mt], 0, 0, 0);
            }
        }
    }

    float* red = (float*)BsH;
    __syncthreads();
    if (kg == 1) {
#pragma unroll
        for (int mt = 0; mt < 2; ++mt)
#pragma unroll
            for (int r = 0; r < 4; ++r)
                red[wq * 512 + mt * 256 + quad * 64 + r * 16 + l16] = acc[mt][r];
    }
    __syncthreads();
    if (kg == 0) {
#pragma unroll
        for (int mt = 0; mt < 2; ++mt)
#pragma unroll
            for (int r = 0; r < 4; ++r) {
                float v = acc[mt][r] + red[wq * 512 + mt * 256 + quad * 64 + r * 16 + l16];
                int m = mt * 16 + quad * 4 + r;
                int n = wq * 16 + l16;
                if (m < 27)
                    om[(size_t)(b * 27 + m) * PXB + hw0 + n] = v + bias[m];
            }
    }
}

// ---------------------------------------------------------------------------
// Fused deformable conv v2 (both layers): M=256 x N=32, 36 rounds x K=64.
// A: SINGLE-buffered wave-private LDS (32KB), global_load_lds DMA; a wave
// overwrites its own region only after its own A ds_reads completed
// (lgkmcnt(0)+sched_barrier before DMA; round barrier drains vmcnt).
// B: dbuf panel. ONE __syncthreads per round. LDS 48896B -> 2 blocks/CU at
// (512,4) with VGPR ~52 (no spill; R18's (512,6) spill cost 45us).
// out_mode 0: NCHW fp32. out_mode 1: NHWC hi/lo bf16 (outH/outL).
// ---------------------------------------------------------------------------
__global__ __launch_bounds__(512, 4) void dfconv_v2(const unsigned short* __restrict__ xB,
                                                    const float* __restrict__ om,
                                                    const unsigned short* __restrict__ A,
                                                    float* __restrict__ out,
                                                    unsigned short* __restrict__ outH,
                                                    unsigned short* __restrict__ outL,
                                                    int out_mode) {
    // arena: Abuf [8][4096]B @0 (32768) | Bbuf0 @32768 (4608) |
    //        Bbuf1 @37376 (4608) | goff @41984 (2304) | gwt @44288 (4608)
    __shared__ __attribute__((aligned(16))) char smem[48896];
    unsigned short* Bbuf0 = (unsigned short*)(smem + 32768);
    unsigned short* Bbuf1 = (unsigned short*)(smem + 37376);
    unsigned short* goff  = (unsigned short*)(smem + 41984);
    float*          gwt   = (float*)(smem + 44288);

    const int tid  = threadIdx.x;
    const int wv   = tid >> 6;
    const int lane = tid & 63;
    const int quad = lane >> 4, l16 = lane & 15;
    const int g    = blockIdx.x;            // 576
    const int nb   = (g & 7) * 72 + (g >> 3);
    const int n0   = nb * 32;
    const int b    = n0 / PXB;
    const int hw0  = n0 - b * PXB;

    // ---- geometry: 32 px x 9 taps ----
    if (tid < 288) {
        int task = tid;
        int px = task / 9;
        int kk = task - px * 9;
        int hw = hw0 + px;
        int h = hw / 96, w = hw - h * 96;
        const float* omp = om + (size_t)b * 27 * PXB + hw;
        float dyv = omp[(size_t)(2 * kk) * PXB];
        float dxv = omp[(size_t)(2 * kk + 1) * PXB];
        float mv  = omp[(size_t)(18 + kk) * PXB];
        float mk  = 1.0f / (1.0f + __expf(-mv));

        float ys = (float)(h + (kk / 3) - 1) + dyv;
        float xs = (float)(w + (kk - (kk / 3) * 3) - 1) + dxv;
        float fy = floorf(ys), fx = floorf(xs);
        int iy = (int)fy, ix = (int)fx;
        float wy1 = ys - fy, wx1 = xs - fx;
        float wy0 = 1.0f - wy1, wx0 = 1.0f - wx1;
        bool yv0 = (unsigned)iy < 96u, yv1 = (unsigned)(iy + 1) < 96u;
        bool xv0 = (unsigned)ix < 96u, xv1 = (unsigned)(ix + 1) < 96u;
        int y0 = min(max(iy, 0), 95),     y1 = min(max(iy + 1, 0), 95);
        int x0 = min(max(ix, 0), 95),     x1 = min(max(ix + 1, 0), 95);
        int gg = task * 4;
        goff[gg + 0] = (unsigned short)(y0 * 96 + x0);
        goff[gg + 1] = (unsigned short)(y0 * 96 + x1);
        goff[gg + 2] = (unsigned short)(y1 * 96 + x0);
        goff[gg + 3] = (unsigned short)(y1 * 96 + x1);
        gwt[gg + 0] = (yv0 && xv0) ? mk * wy0 * wx0 : 0.0f;
        gwt[gg + 1] = (yv0 && xv1) ? mk * wy0 * wx1 : 0.0f;
        gwt[gg + 2] = (yv1 && xv0) ? mk * wy1 * wx0 : 0.0f;
        gwt[gg + 3] = (yv1 && xv1) ? mk * wy1 * wx1 : 0.0f;
    }
    __syncthreads();

    // ---- roles ----
    const int px = (tid & 255) >> 3;        // staging (tid<256)
    const int cg = tid & 7;
    const unsigned short* xbase = xB + (size_t)b * PXB * 256 + cg * 8;

    // A DMA lane mapping: shot s covers rows wv*32+s*8+(lane>>3); granule slot
    // lane&7 holds global granule (lane&7)^(lane>>3)  [XOR source swizzle].
    const int arl = lane >> 3;               // 0..7
    const int akg = (lane & 7) ^ arl;        // swizzled source granule

    f32x4 acc[2][2];
#pragma unroll
    for (int mt = 0; mt < 2; ++mt)
#pragma unroll
        for (int nt = 0; nt < 2; ++nt) acc[mt][nt] = (f32x4)0.0f;

    auto dmaA = [&](int kt) {
#pragma unroll
        for (int s = 0; s < 4; ++s) {
            const unsigned short* src =
                A + (size_t)(wv * 32 + s * 8 + arl) * KTOT + kt * 64 + akg * 8;
            char* dst = smem + wv * 4096 + s * 1024;
            __builtin_amdgcn_global_load_lds(
                (const __attribute__((address_space(1))) unsigned int*)src,
                (__attribute__((address_space(3))) unsigned int*)dst, 16, 0, 0);
        }
    };

    // ---- prologue: A(0) DMA, corners(0) -> interp -> Bbuf0 ----
    dmaA(0);
    if (tid < 256) {
        int gg = (px * 9 + 0) * 4;          // kt=0: tap 0, c0 0
        ushort4 o4 = *(const ushort4*)&goff[gg];
        float4 wt = *(const float4*)&gwt[gg];
        uint4 u0 = *(const uint4*)(xbase + (size_t)o4.x * 256);
        uint4 u1 = *(const uint4*)(xbase + (size_t)o4.y * 256);
        uint4 u2 = *(const uint4*)(xbase + (size_t)o4.z * 256);
        uint4 u3 = *(const uint4*)(xbase + (size_t)o4.w * 256);
        float f0[8], f1[8], f2[8], f3[8];
        unpack8(u0, f0); unpack8(u1, f1); unpack8(u2, f2); unpack8(u3, f3);
        unsigned short res[8];
#pragma unroll
        for (int j = 0; j < 8; ++j)
            res[j] = f2bf(wt.x * f0[j] + wt.y * f1[j] + wt.z * f2[j] + wt.w * f3[j]);
        *(uint4*)&Bbuf0[px * 72 + cg * 8] = *(uint4*)res;
    }
    __syncthreads();    // A(0) drained, B(0) visible

    // ---- main loop: ONE barrier per round, single wave-private Abuf ----
    for (int r = 0; r < 36; ++r) {
        const int cur = r & 1;

        // 1. issue next round's corners (max latency cover)
        uint4 cc0, cc1, cc2, cc3; float4 wt;
        if (tid < 256 && r < 35) {
            const int ktn = r + 1, tap = ktn >> 2, c0 = (ktn & 3) * 64;
            int gg = (px * 9 + tap) * 4;
            ushort4 o4 = *(const ushort4*)&goff[gg];
            wt = *(const float4*)&gwt[gg];
            const unsigned short* cb = xbase + c0;
            cc0 = *(const uint4*)(cb + (size_t)o4.x * 256);
            cc1 = *(const uint4*)(cb + (size_t)o4.y * 256);
            cc2 = *(const uint4*)(cb + (size_t)o4.z * 256);
            cc3 = *(const uint4*)(cb + (size_t)o4.w * 256);
        }

        // 2. A-fragments: LDS -> regs (wave-private region)
        bf16x8 af00, af01, af10, af11;
        {
            const char* Ac = smem + wv * 4096;
            const int sw0 = ((quad ^ (l16 & 7)) * 16);
            const int sw1 = (((4 + quad) ^ (l16 & 7)) * 16);
            af00 = *(const bf16x8*)(Ac + l16 * 128 + sw0);
            af01 = *(const bf16x8*)(Ac + (16 + l16) * 128 + sw0);
            af10 = *(const bf16x8*)(Ac + l16 * 128 + sw1);
            af11 = *(const bf16x8*)(Ac + (16 + l16) * 128 + sw1);
        }
        // A reads complete before overwrite; fence per rule #18
        asm volatile("s_waitcnt lgkmcnt(0)" ::: "memory");
        __builtin_amdgcn_sched_barrier(0);

        // 3. DMA A(r+1) into the SAME wave-private region (safe post-read)
        if (r < 35) dmaA(r + 1);

        // 4. MFMA (A from regs, B from LDS)
        {
            const unsigned short* Br = cur ? Bbuf1 : Bbuf0;
            bf16x8 b0 = *(const bf16x8*)&Br[l16 * 72 + quad * 8];
            bf16x8 b1 = *(const bf16x8*)&Br[(16 + l16) * 72 + quad * 8];
            acc[0][0] = __builtin_amdgcn_mfma_f32_16x16x32_bf16(af00, b0, acc[0][0], 0, 0, 0);
            acc[0][1] = __builtin_amdgcn_mfma_f32_16x16x32_bf16(af00, b1, acc[0][1], 0, 0, 0);
            acc[1][0] = __builtin_amdgcn_mfma_f32_16x16x32_bf16(af01, b0, acc[1][0], 0, 0, 0);
            acc[1][1] = __builtin_amdgcn_mfma_f32_16x16x32_bf16(af01, b1, acc[1][1], 0, 0, 0);
            bf16x8 b2 = *(const bf16x8*)&Br[l16 * 72 + 32 + quad * 8];
            bf16x8 b3 = *(const bf16x8*)&Br[(16 + l16) * 72 + 32 + quad * 8];
            acc[0][0] = __builtin_amdgcn_mfma_f32_16x16x32_bf16(af10, b2, acc[0][0], 0, 0, 0);
            acc[0][1] = __builtin_amdgcn_mfma_f32_16x16x32_bf16(af10, b3, acc[0][1], 0, 0, 0);
            acc[1][0] = __builtin_amdgcn_mfma_f32_16x16x32_bf16(af11, b2, acc[1][0], 0, 0, 0);
            acc[1][1] = __builtin_amdgcn_mfma_f32_16x16x32_bf16(af11, b3, acc[1][1], 0, 0, 0);
        }

        // 5. interp next round's corners -> other B buffer
        if (tid < 256 && r < 35) {
            unsigned short* Bw = cur ? Bbuf0 : Bbuf1;
            float f0[8], f1[8], f2[8], f3[8];
            unpack8(cc0, f0); unpack8(cc1, f1); unpack8(cc2, f2); unpack8(cc3, f3);
            unsigned short res[8];
#pragma unroll
            for (int j = 0; j < 8; ++j)
                res[j] = f2bf(wt.x * f0[j] + wt.y * f1[j] + wt.z * f2[j] + wt.w * f3[j]);
            *(uint4*)&Bw[px * 72 + cg * 8] = *(uint4*)res;
        }

        __syncthreads();    // DMA drained (A(r+1) ready), B(next) visible
    }

    // ---- epilogues: tileS aliases smem ----
    float* tileS = (float*)smem;
    if (out_mode == 0) {
        // NCHW out[b][m][hw0..+31]: 2 passes of 128 m; tileS[128][36]
#pragma unroll
        for (int pass = 0; pass < 2; ++pass) {
            if ((wv >> 2) == pass) {
#pragma unroll
                for (int mt = 0; mt < 2; ++mt)
#pragma unroll
                    for (int nt = 0; nt < 2; ++nt)
#pragma unroll
                        for (int rr = 0; rr < 4; ++rr) {
                            int ml = (wv & 3) * 32 + mt * 16 + quad * 4 + rr;
                            int n  = nt * 16 + l16;
                            tileS[ml * 36 + n] = fmaxf(acc[mt][nt][rr], 0.0f);
                        }
            }
            __syncthreads();
#pragma unroll
            for (int j = 0; j < 2; ++j) {
                int idx = j * 512 + tid;
                int row = idx >> 3, q = idx & 7;
                *(float4*)&out[(size_t)(b * 256 + pass * 128 + row) * PXB + hw0 + q * 4] =
                    *(const float4*)&tileS[row * 36 + q * 4];
            }
            __syncthreads();
        }
    } else {
        // NHWC hi/lo bf16 (outH/outL): 2 passes of 16 px; tileS[16][264]
#pragma unroll
        for (int pass = 0; pass < 2; ++pass) {
#pragma unroll
            for (int mt = 0; mt < 2; ++mt) {
                f32x4 v = acc[mt][pass];
                v[0] = fmaxf(v[0], 0.f); v[1] = fmaxf(v[1], 0.f);
                v[2] = fmaxf(v[2], 0.f); v[3] = fmaxf(v[3], 0.f);
                *(f32x4*)&tileS[l16 * 264 + wv * 32 + mt * 16 + quad * 4] = v;
            }
            __syncthreads();
#pragma unroll
            for (int j = 0; j < 2; ++j) {
                int idx = j * 512 + tid;
                int pxl = idx >> 6, ln = idx & 63;
                float4 v = *(const float4*)&tileS[pxl * 264 + ln * 4];
                size_t oi = ((size_t)b * PXB + hw0 + pass * 16 + pxl) * 256 + ln * 4;
                unsigned short hv[4], lv[4];
#pragma unroll
                for (int e = 0; e < 4; ++e) {
                    float fe = (e == 0) ? v.x : (e == 1) ? v.y : (e == 2) ? v.z : v.w;
                    hv[e] = f2bf(fe);
                    lv[e] = f2bf(fe - bf2f(hv[e]));
                }
                *(ushort4*)&outH[oi] = *(ushort4*)hv;
                *(ushort4*)&outL[oi] = *(ushort4*)lv;
            }
            __syncthreads();
        }
    }
}

// ---------------------------------------------------------------------------
extern "C" void kernel_launch(void* const* d_in, const int* in_sizes, int n_in,
                              void* d_out, int out_size, void* d_ws, size_t ws_size,
                              hipStream_t stream) {
    const float* x     = (const float*)d_in[0];
    const float* woff0 = (const float*)d_in[1];
    const float* boff0 = (const float*)d_in[2];
    const float* w0    = (const float*)d_in[3];
    const float* woff1 = (const float*)d_in[4];
    const float* boff1 = (const float*)d_in[5];
    const float* w1    = (const float*)d_in[6];
    float* out = (float*)d_out;

    char* p = (char*)d_ws;
    float* om  = (float*)p;  p += (size_t)2 * 27 * PXB * 4;               // 2.0 MB
    unsigned short* xh  = (unsigned short*)p; p += (size_t)2 * 256 * PXB * 2;  // 9.4 MB
    unsigned short* xl  = (unsigned short*)p; p += (size_t)2 * 256 * PXB * 2;  // 9.4 MB
    unsigned short* h1h = (unsigned short*)p; p += (size_t)2 * 256 * PXB * 2;  // 9.4 MB
    unsigned short* h1l = (unsigned short*)p; p += (size_t)2 * 256 * PXB * 2;  // 9.4 MB
    unsigned short* wA0 = (unsigned short*)p; p += (size_t)256 * KTOT * 2;
    unsigned short* wA1 = (unsigned short*)p; p += (size_t)256 * KTOT * 2;
    unsigned short* wH0 = (unsigned short*)p; p += (size_t)32 * KTOT * 2;
    unsigned short* wL0 = (unsigned short*)p; p += (size_t)32 * KTOT * 2;
    unsigned short* wH1 = (unsigned short*)p; p += (size_t)32 * KTOT * 2;
    unsigned short* wL1 = (unsigned short*)p; p += (size_t)32 * KTOT * 2;

    hipLaunchKernelGGL(transpose_kernel, dim3(PXB / 64, 4, 2), dim3(256), 0, stream, x, xh, xl);
    hipLaunchKernelGGL(prep_w_kernel, dim3(256 * KTOT / 256), dim3(256), 0, stream, w0, wA0);
    hipLaunchKernelGGL(prep_w_kernel, dim3(256 * KTOT / 256), dim3(256), 0, stream, w1, wA1);
    hipLaunchKernelGGL(prep_woff_kernel, dim3(32 * KTOT / 256), dim3(256), 0, stream, woff0, wH0, wL0);
    hipLaunchKernelGGL(prep_woff_kernel, dim3(32 * KTOT / 256), dim3(256), 0, stream, woff1, wH1, wL1);

    // Layer 0: x -> h1 (NHWC hi/lo bf16)
    hipLaunchKernelGGL(offconv_fused, dim3(288), dim3(512), 0, stream, xh, xl, wH0, wL0, boff0, om);
    hipLaunchKernelGGL(dfconv_v2, dim3(576), dim3(512), 0, stream, xh, om, wA0,
                       (float*)nullptr, h1h, h1l, 1);

    // Layer 1: h1 -> out (NCHW fp32)
    hipLaunchKernelGGL(offconv_fused, dim3(288), dim3(512), 0, stream, h1h, h1l, wH1, wL1, boff1, om);
    hipLaunchKernelGGL(dfconv_v2, dim3(576), dim3(512), 0, stream, h1h, om, wA1,
                       out, (unsigned short*)nullptr, (unsigned short*)nullptr, 0);
}